// Round 3
// baseline (182.150 us; speedup 1.0000x reference)
//
#include <hip/hip_runtime.h>

#define H 1024
#define HH (H * H)          // 1048576 per channel plane
#define CHW (3 * HH)        // 3145728 per image
#define NB 256
#define NTHR 256
#define NGR (HH / 4)        // 262144 pixel-groups (4 pixels each)
#define NBLK (NGR / NTHR)   // 1024 blocks: exactly 1 group per thread
#define CNT_BLOCKS 512
#define FIN_BLOCKS 512

__device__ __forceinline__ float clamp01(float x) { return fminf(fmaxf(x, 0.0f), 1.0f); }

// bin of a value already divided by 255 (v01 = masked_value/255, mask in {0,1})
// (int)(v01*255) is bit-exact vs reference's (int)(clamp01(..)*255*mask).
__device__ __forceinline__ unsigned int bin8(float v01) {
    int b = (int)(v01 * 255.0f);
    return (unsigned int)min(max(b, 0), NB - 1);
}

// ---------------------------------------------------------------------------
// Stage 1: per-pixel multiplicity counts from the index arrays ONLY.
// Byte-packed 4 pixels/u32 (max multiplicity ~9 << 255 for this fixed input).
// The histogram over the sampled multiset == dense weighted pass
// hist[c][bin(pix)] += cnt[pix] — this removes ALL random gathers (the old
// k_hist read pk_dst/pk_ref at 800K random 4B locations, latency-bound) and
// the whole 16MB pk round-trip. cnt arrays are zeroed by the preceding
// hipMemsetAsync; kernel boundary makes counts visible to k_elementwise.
// ---------------------------------------------------------------------------
__global__ void k_count(const int* __restrict__ i0, const int* __restrict__ i1,
                        const int* __restrict__ i2, const int* __restrict__ i3,
                        unsigned int* __restrict__ cntd, unsigned int* __restrict__ cntr,
                        float* __restrict__ loss, int n)
{
    if (blockIdx.x == 0 && threadIdx.x == 0) *loss = 0.0f;
    int stride = gridDim.x * blockDim.x;
    for (int k = blockIdx.x * blockDim.x + threadIdx.x; k < n; k += stride) {
        int pd = i0[k] * H + i1[k];
        int pr = i2[k] * H + i3[k];
        atomicAdd(&cntd[pd >> 2], 1u << (8 * (pd & 3)));
        atomicAdd(&cntr[pr >> 2], 1u << (8 * (pr & 3)));
    }
}

// ---------------------------------------------------------------------------
// Stage 2: elementwise masking + INLINE weighted histogram.
// Each thread owns exactly one 4-pixel group: bins stay in registers, the
// thread reads its own coalesced cnt words (ready from k_count), does
// weighted LDS atomics, block-merges to ghist. ~68% of pixels have weight 0
// (skipped). No pk arrays, no out3 copy.
// ---------------------------------------------------------------------------
__global__ __launch_bounds__(NTHR)
void k_elementwise(const float4* __restrict__ inp, const float4* __restrict__ tar,
                   const float4* __restrict__ rfp, const float4* __restrict__ msrc,
                   const float4* __restrict__ mtar,
                   float4* __restrict__ out0, float4* __restrict__ out1,
                   float4* __restrict__ out2,
                   const unsigned int* __restrict__ cntd,
                   const unsigned int* __restrict__ cntr,
                   unsigned int* __restrict__ ghist)
{
    __shared__ unsigned int h[6 * NB];   // rows 0-2 dst(=ref_masked), 3-5 ref(=target_masked)
    for (int i = threadIdx.x; i < 6 * NB; i += NTHR) h[i] = 0u;
    __syncthreads();

    const int p = blockIdx.x * NTHR + threadIdx.x;   // group id (grid exact)

    float4 ms4 = msrc[p], mt4 = mtar[p];
    // true division: 255.0f/255.0f == 1.0f exactly
    float msx = ms4.x / 255.0f, msy = ms4.y / 255.0f, msz = ms4.z / 255.0f, msw = ms4.w / 255.0f;
    float mtx = mt4.x / 255.0f, mty = mt4.y / 255.0f, mtz = mt4.z / 255.0f, mtw = mt4.w / 255.0f;
    unsigned int bd[4] = {0u, 0u, 0u, 0u};   // packed bins of o1, pixel j, byte c = channel
    unsigned int br[4] = {0u, 0u, 0u, 0u};   // packed bins of o0
#pragma unroll
    for (int c = 0; c < 3; ++c) {
        int q = c * NGR + p;
        float4 tv = tar[q], rv = rfp[q], iv = inp[q];
        float4 o0, o1, o2;
        o0.x = clamp01((tv.x + 1.0f) * 0.5f) * mtx;
        o0.y = clamp01((tv.y + 1.0f) * 0.5f) * mty;
        o0.z = clamp01((tv.z + 1.0f) * 0.5f) * mtz;
        o0.w = clamp01((tv.w + 1.0f) * 0.5f) * mtw;
        o1.x = clamp01((rv.x + 1.0f) * 0.5f) * msx;
        o1.y = clamp01((rv.y + 1.0f) * 0.5f) * msy;
        o1.z = clamp01((rv.z + 1.0f) * 0.5f) * msz;
        o1.w = clamp01((rv.w + 1.0f) * 0.5f) * msw;
        o2.x = clamp01(iv.x) * msx;
        o2.y = clamp01(iv.y) * msy;
        o2.z = clamp01(iv.z) * msz;
        o2.w = clamp01(iv.w) * msw;
        out0[q] = o0;
        out1[q] = o1;
        out2[q] = o2;
        int sh = 8 * c;
        bd[0] |= bin8(o1.x) << sh;  bd[1] |= bin8(o1.y) << sh;
        bd[2] |= bin8(o1.z) << sh;  bd[3] |= bin8(o1.w) << sh;
        br[0] |= bin8(o0.x) << sh;  br[1] |= bin8(o0.y) << sh;
        br[2] |= bin8(o0.z) << sh;  br[3] |= bin8(o0.w) << sh;
    }

    unsigned int wd = cntd[p], wr = cntr[p];
#pragma unroll
    for (int j = 0; j < 4; ++j) {
        unsigned int wj = (wd >> (8 * j)) & 255u;
        if (wj) {
            unsigned int b = bd[j];
            atomicAdd(&h[        (b        & 255u)], wj);
            atomicAdd(&h[  NB + ((b >>  8) & 255u)], wj);
            atomicAdd(&h[2*NB + ((b >> 16) & 255u)], wj);
        }
        unsigned int vj = (wr >> (8 * j)) & 255u;
        if (vj) {
            unsigned int b = br[j];
            atomicAdd(&h[3*NB + ( b        & 255u)], vj);
            atomicAdd(&h[4*NB + ((b >>  8) & 255u)], vj);
            atomicAdd(&h[5*NB + ((b >> 16) & 255u)], vj);
        }
    }
    __syncthreads();
    for (int i = threadIdx.x; i < 6 * NB; i += NTHR) {
        unsigned int v = h[i];
        if (v) atomicAdd(&ghist[i], v);
    }
}

// ---------------------------------------------------------------------------
// Stage 3 (fused tables + out3 + loss) — verified R1 structure.
// Every block redundantly computes the transfer tables from ghist (6KB
// L2-hot read + wave scan + 8-step binary search; identical float compares
// to the verified k_tables), then streams out3 densely:
//   out3[p] = (cnt byte != 0) ? table[bin8(out1[p])] : out1[p]
// accumulating loss = mean|out2 - out3| in the same pass. Marked flags come
// straight from cntd[k] bytes (coalesced 1MB read).
// ---------------------------------------------------------------------------
__global__ __launch_bounds__(384)
void k_finalize(const uint4* __restrict__ ghist4,
                const unsigned int* __restrict__ cntd,
                const float4* __restrict__ out1v,
                const float4* __restrict__ out2v,
                float4* __restrict__ out3v,
                float* __restrict__ loss)
{
    __shared__ float cdf[6][NB];     // rows 0-2: cdf_dst, rows 3-5: cdf_ref
    __shared__ float tl[3 * NB];     // tables, PRE-DIVIDED by 255
    __shared__ float ws[6];
    int t = threadIdx.x;
    int wave = t >> 6, lane = t & 63;

    // --- per-block table compute (6 waves, one histogram row each) ---
    uint4 v = ghist4[wave * 64 + lane];
    unsigned int s0 = v.x;
    unsigned int s1 = s0 + v.y;
    unsigned int s2 = s1 + v.z;
    unsigned int s3 = s2 + v.w;

    unsigned int scan = s3;
#pragma unroll
    for (int off = 1; off < 64; off <<= 1) {
        unsigned int u = (unsigned int)__shfl_up((int)scan, off, 64);
        if (lane >= off) scan += u;
    }
    unsigned int prefix = scan - s3;
    unsigned int total  = (unsigned int)__shfl((int)scan, 63, 64);
    float ft = (float)total;

    cdf[wave][lane * 4 + 0] = (float)(prefix + s0) / ft;
    cdf[wave][lane * 4 + 1] = (float)(prefix + s1) / ft;
    cdf[wave][lane * 4 + 2] = (float)(prefix + s2) / ft;
    cdf[wave][lane * 4 + 3] = (float)(prefix + s3) / ft;
    __syncthreads();

    if (t < NB) {
#pragma unroll
        for (int c = 0; c < 3; ++c) {
            float r = cdf[c][t];
            const float* cr = cdf[3 + c];
            int lo = 1, hi = NB - 1;
#pragma unroll
            for (int it = 0; it < 8; ++it) {
                int mid = (lo + hi) >> 1;
                if (cr[mid] >= r) hi = mid; else lo = mid + 1;
            }
            int jstar = lo - 1;
            int tab = (jstar == 0 && cr[0] > r) ? t : (jstar + 1);
            if (t == NB - 1) tab = NB - 1;
            tl[c * NB + t] = (float)tab / 255.0f;
        }
    }
    __syncthreads();

    // --- dense out3 + loss streaming pass ---
    float s = 0.0f;
    const int n4 = HH / 4;
    for (int k = blockIdx.x * blockDim.x + t; k < n4; k += gridDim.x * blockDim.x) {
        unsigned int w = cntd[k];   // bytes = multiplicities of pixels 4k..4k+3
#pragma unroll
        for (int c = 0; c < 3; ++c) {
            float4 a = out1v[c * n4 + k];
            float4 b = out2v[c * n4 + k];
            float4 o;
            o.x = ( w        & 255u) ? tl[c * NB + bin8(a.x)] : a.x;
            o.y = ((w >>  8) & 255u) ? tl[c * NB + bin8(a.y)] : a.y;
            o.z = ((w >> 16) & 255u) ? tl[c * NB + bin8(a.z)] : a.z;
            o.w = ( w >> 24        ) ? tl[c * NB + bin8(a.w)] : a.w;
            out3v[c * n4 + k] = o;
            s += fabsf(b.x - o.x) + fabsf(b.y - o.y) + fabsf(b.z - o.z) + fabsf(b.w - o.w);
        }
    }
#pragma unroll
    for (int off = 32; off > 0; off >>= 1) s += __shfl_down(s, off);
    if (lane == 0) ws[wave] = s;
    __syncthreads();
    if (t == 0) {
        float tsum = ws[0] + ws[1] + ws[2] + ws[3] + ws[4] + ws[5];
        atomicAdd(loss, tsum * (1.0f / (float)CHW));
    }
}

extern "C" void kernel_launch(void* const* d_in, const int* in_sizes, int n_in,
                              void* d_out, int out_size, void* d_ws, size_t ws_size,
                              hipStream_t stream)
{
    const float* inp  = (const float*)d_in[0];
    const float* tar  = (const float*)d_in[1];
    const float* rfp  = (const float*)d_in[2];
    const float* msrc = (const float*)d_in[3];
    const float* mtar = (const float*)d_in[4];
    // d_in[5] = target_data_eye (unused by the reference computation)
    const int* i0 = (const int*)d_in[6];
    const int* i1 = (const int*)d_in[7];
    const int* i2 = (const int*)d_in[8];
    const int* i3 = (const int*)d_in[9];
    int n = in_sizes[6];

    float* out0 = (float*)d_out;
    float* out1 = out0 + CHW;
    float* out2 = out1 + CHW;
    float* out3 = out2 + CHW;
    float* loss = out3 + CHW;

    // workspace layout
    unsigned int* ghist = (unsigned int*)d_ws;                    // [0, 6144): 1536 u32
    unsigned int* cntd  = (unsigned int*)((char*)d_ws + 8192);    // NGR u32, byte-packed counts (1 MB)
    unsigned int* cntr  = cntd + NGR;                             // NGR u32 (1 MB)

    // zero ghist + both count arrays in one stream memset (graph-capturable)
    hipMemsetAsync(d_ws, 0, 8192 + 2 * (size_t)NGR * 4, stream);

    k_count<<<CNT_BLOCKS, 256, 0, stream>>>(i0, i1, i2, i3, cntd, cntr, loss, n);

    k_elementwise<<<NBLK, NTHR, 0, stream>>>(
        (const float4*)inp, (const float4*)tar, (const float4*)rfp,
        (const float4*)msrc, (const float4*)mtar,
        (float4*)out0, (float4*)out1, (float4*)out2,
        cntd, cntr, ghist);

    k_finalize<<<FIN_BLOCKS, 384, 0, stream>>>(
        (const uint4*)ghist, cntd, (const float4*)out1, (const float4*)out2,
        (float4*)out3, loss);
}

// Round 4
// 170.715 us; speedup vs baseline: 1.0670x; 1.0670x over previous
//
#include <hip/hip_runtime.h>

#define H 1024
#define HH (H * H)          // 1048576 per channel plane
#define CHW (3 * HH)        // 3145728 per image
#define NB 256
#define HIST_BLOCKS 512     // R4: 2 blocks/CU exactly. 768 gave ~1 sample/thread, so per-block
                            // fixed cost (6KB LDS zero + 1536-atomic ghist merge) rivaled the
                            // sample work; 512 cuts merge atomics 1.18M->786K at full gather TLP.
#define FIN_BLOCKS 512      // 2 blocks/CU x 6 waves = 12 waves/CU for the streaming pass

__device__ __forceinline__ float clamp01(float x) { return fminf(fmaxf(x, 0.0f), 1.0f); }

// bin of a value already divided by 255 (v01 = masked_value/255, mask in {0,1})
// (int)(v01*255) is bit-exact vs reference's (int)(clamp01(..)*255*mask).
__device__ __forceinline__ unsigned int bin8(float v01) {
    int b = (int)(v01 * 255.0f);
    return (unsigned int)min(max(b, 0), NB - 1);
}

// ---------------------------------------------------------------------------
// Stage 1: elementwise masking + packed per-pixel bin triples.
// No out3 copy (k_finalize produces out3 densely). Block 0 zeroes
// ghist[1536] + loss; blocks 1..32 zero the 128KB scatter bitmap
// (kernel-boundary ordering guarantees visibility to k_hist).
// [R3 post-mortem: count-based hist (memset+k_count scatter atomics) measured
//  +7us vs this gather structure — pk is L3-hot for k_hist, gathers are cheap.]
// ---------------------------------------------------------------------------
__global__ void k_elementwise(const float4* __restrict__ inp,
                              const float4* __restrict__ tar,
                              const float4* __restrict__ rfp,
                              const float4* __restrict__ msrc,
                              const float4* __restrict__ mtar,
                              float4* __restrict__ out0, float4* __restrict__ out1,
                              float4* __restrict__ out2,
                              uint4* __restrict__ pk_dst, uint4* __restrict__ pk_ref,
                              unsigned int* __restrict__ gz,
                              unsigned int* __restrict__ bm,
                              float* __restrict__ loss)
{
    if (blockIdx.x == 0) {
        for (int i = threadIdx.x; i < 1536; i += blockDim.x) gz[i] = 0u;  // ghist
        if (threadIdx.x == 0) *loss = 0.0f;
    } else if (blockIdx.x <= 32) {
        int base = (int)(blockIdx.x - 1) * 1024;
        for (int i = threadIdx.x; i < 1024; i += blockDim.x) bm[base + i] = 0u;  // bitmap
    }
    int p = blockIdx.x * blockDim.x + threadIdx.x;
    if (p >= HH / 4) return;
    float4 ms4 = msrc[p], mt4 = mtar[p];
    // true division: 255.0f/255.0f == 1.0f exactly
    float msx = ms4.x / 255.0f, msy = ms4.y / 255.0f, msz = ms4.z / 255.0f, msw = ms4.w / 255.0f;
    float mtx = mt4.x / 255.0f, mty = mt4.y / 255.0f, mtz = mt4.z / 255.0f, mtw = mt4.w / 255.0f;
    unsigned int bd0 = 0, bd1 = 0, bd2 = 0, bd3 = 0;
    unsigned int br0 = 0, br1 = 0, br2 = 0, br3 = 0;
#pragma unroll
    for (int c = 0; c < 3; ++c) {
        int q = c * (HH / 4) + p;
        float4 t = tar[q], r = rfp[q], iv = inp[q];
        float4 o0, o1, o2;
        o0.x = clamp01((t.x + 1.0f) * 0.5f) * mtx;
        o0.y = clamp01((t.y + 1.0f) * 0.5f) * mty;
        o0.z = clamp01((t.z + 1.0f) * 0.5f) * mtz;
        o0.w = clamp01((t.w + 1.0f) * 0.5f) * mtw;
        o1.x = clamp01((r.x + 1.0f) * 0.5f) * msx;
        o1.y = clamp01((r.y + 1.0f) * 0.5f) * msy;
        o1.z = clamp01((r.z + 1.0f) * 0.5f) * msz;
        o1.w = clamp01((r.w + 1.0f) * 0.5f) * msw;
        o2.x = clamp01(iv.x) * msx;
        o2.y = clamp01(iv.y) * msy;
        o2.z = clamp01(iv.z) * msz;
        o2.w = clamp01(iv.w) * msw;
        out0[q] = o0;
        out1[q] = o1;
        out2[q] = o2;
        int sh = 8 * c;
        bd0 |= bin8(o1.x) << sh;  bd1 |= bin8(o1.y) << sh;
        bd2 |= bin8(o1.z) << sh;  bd3 |= bin8(o1.w) << sh;
        br0 |= bin8(o0.x) << sh;  br1 |= bin8(o0.y) << sh;
        br2 |= bin8(o0.z) << sh;  br3 |= bin8(o0.w) << sh;
    }
    pk_dst[p] = make_uint4(bd0, bd1, bd2, bd3);
    pk_ref[p] = make_uint4(br0, br1, br2, br3);
}

// ---------------------------------------------------------------------------
// Stage 2: histograms from packed bins + scatter-pixel bitmap mark.
// pk arrays are L3-hot (written by stage 1); 800K random 4B gathers hidden by
// 262K threads of TLP. Bitmap mark (atomicOr, idempotent) reuses pd.
// Ballot aggregation for fully-zero packed values (~30% of samples are
// masked-out -> bins {0,0,0}): one atomicAdd per wave instead of up to 64
// serialized same-address adds. Count semantics identical.
// ---------------------------------------------------------------------------
__global__ void k_hist(const unsigned int* __restrict__ pk_dst,
                       const unsigned int* __restrict__ pk_ref,
                       const int* __restrict__ i0, const int* __restrict__ i1,
                       const int* __restrict__ i2, const int* __restrict__ i3,
                       unsigned int* __restrict__ ghist,
                       unsigned int* __restrict__ bm, int n)
{
    __shared__ unsigned int h[2 * 3 * NB];
    for (int i = threadIdx.x; i < 2 * 3 * NB; i += blockDim.x) h[i] = 0u;
    __syncthreads();

    int lane = threadIdx.x & 63;
    for (int k = blockIdx.x * blockDim.x + threadIdx.x; k < n; k += gridDim.x * blockDim.x) {
        int pd = i0[k] * H + i1[k];
        int pr = i2[k] * H + i3[k];
        unsigned int a = pk_dst[pd];
        unsigned int b = pk_ref[pr];

        atomicOr(&bm[(unsigned int)pd >> 5], 1u << (pd & 31));

        unsigned long long mza = __ballot(a == 0u);
        if (a != 0u) {
            atomicAdd(&h[        (a       & 255u)], 1u);
            atomicAdd(&h[  NB + ((a >> 8) & 255u)], 1u);
            atomicAdd(&h[2*NB + ((a >>16) & 255u)], 1u);
        } else if (lane == __ffsll(mza) - 1) {
            unsigned int cnt = (unsigned int)__popcll(mza);
            atomicAdd(&h[0],      cnt);
            atomicAdd(&h[NB],     cnt);
            atomicAdd(&h[2 * NB], cnt);
        }

        unsigned long long mzb = __ballot(b == 0u);
        if (b != 0u) {
            atomicAdd(&h[3*NB + ( b       & 255u)], 1u);
            atomicAdd(&h[4*NB + ((b >> 8) & 255u)], 1u);
            atomicAdd(&h[5*NB + ((b >>16) & 255u)], 1u);
        } else if (lane == __ffsll(mzb) - 1) {
            unsigned int cnt = (unsigned int)__popcll(mzb);
            atomicAdd(&h[3 * NB], cnt);
            atomicAdd(&h[4 * NB], cnt);
            atomicAdd(&h[5 * NB], cnt);
        }
    }
    __syncthreads();
    for (int i = threadIdx.x; i < 2 * 3 * NB; i += blockDim.x) {
        unsigned int v = h[i];
        if (v) atomicAdd(&ghist[i], v);
    }
}

// ---------------------------------------------------------------------------
// Stage 3 (fused tables + out3 + loss). Every block redundantly computes the
// cdf/transfer table from ghist (6KB L2-hot read + wave scan + 8-step binary
// search; identical float compares to the verified k_tables), then streams
// out3 densely:
//   out3[p] = marked(p) ? table[bin8(out1[p])] : out1[p]
// accumulating loss = mean|out2 - out3| in the same pass. out1/out2 re-reads
// are L3-hot (written by stage 1).
// ---------------------------------------------------------------------------
__global__ __launch_bounds__(384)
void k_finalize(const uint4* __restrict__ ghist4,
                const unsigned int* __restrict__ bm,
                const float4* __restrict__ out1v,
                const float4* __restrict__ out2v,
                float4* __restrict__ out3v,
                float* __restrict__ loss)
{
    __shared__ float cdf[6][NB];     // rows 0-2: cdf_dst, rows 3-5: cdf_ref
    __shared__ float tl[3 * NB];     // tables, PRE-DIVIDED by 255
    __shared__ float ws[6];
    int t = threadIdx.x;
    int wave = t >> 6, lane = t & 63;

    // --- per-block table compute (6 waves, one histogram row each) ---
    uint4 v = ghist4[wave * 64 + lane];
    unsigned int s0 = v.x;
    unsigned int s1 = s0 + v.y;
    unsigned int s2 = s1 + v.z;
    unsigned int s3 = s2 + v.w;

    unsigned int scan = s3;
#pragma unroll
    for (int off = 1; off < 64; off <<= 1) {
        unsigned int u = (unsigned int)__shfl_up((int)scan, off, 64);
        if (lane >= off) scan += u;
    }
    unsigned int prefix = scan - s3;
    unsigned int total  = (unsigned int)__shfl((int)scan, 63, 64);
    float ft = (float)total;

    cdf[wave][lane * 4 + 0] = (float)(prefix + s0) / ft;
    cdf[wave][lane * 4 + 1] = (float)(prefix + s1) / ft;
    cdf[wave][lane * 4 + 2] = (float)(prefix + s2) / ft;
    cdf[wave][lane * 4 + 3] = (float)(prefix + s3) / ft;
    __syncthreads();

    if (t < NB) {
#pragma unroll
        for (int c = 0; c < 3; ++c) {
            float r = cdf[c][t];
            const float* cr = cdf[3 + c];
            int lo = 1, hi = NB - 1;
#pragma unroll
            for (int it = 0; it < 8; ++it) {
                int mid = (lo + hi) >> 1;
                if (cr[mid] >= r) hi = mid; else lo = mid + 1;
            }
            int jstar = lo - 1;
            int tab = (jstar == 0 && cr[0] > r) ? t : (jstar + 1);
            if (t == NB - 1) tab = NB - 1;
            tl[c * NB + t] = (float)tab / 255.0f;
        }
    }
    __syncthreads();

    // --- dense out3 + loss streaming pass ---
    float s = 0.0f;
    const int n4 = HH / 4;
    for (int k = blockIdx.x * blockDim.x + t; k < n4; k += gridDim.x * blockDim.x) {
        unsigned int w = bm[k >> 3];
        unsigned int nib = (w >> ((k & 7) * 4)) & 0xFu;   // flags for pixels 4k..4k+3
#pragma unroll
        for (int c = 0; c < 3; ++c) {
            float4 a = out1v[c * n4 + k];
            float4 b = out2v[c * n4 + k];
            float4 o;
            o.x = (nib & 1u) ? tl[c * NB + bin8(a.x)] : a.x;
            o.y = (nib & 2u) ? tl[c * NB + bin8(a.y)] : a.y;
            o.z = (nib & 4u) ? tl[c * NB + bin8(a.z)] : a.z;
            o.w = (nib & 8u) ? tl[c * NB + bin8(a.w)] : a.w;
            out3v[c * n4 + k] = o;
            s += fabsf(b.x - o.x) + fabsf(b.y - o.y) + fabsf(b.z - o.z) + fabsf(b.w - o.w);
        }
    }
#pragma unroll
    for (int off = 32; off > 0; off >>= 1) s += __shfl_down(s, off);
    if (lane == 0) ws[wave] = s;
    __syncthreads();
    if (t == 0) {
        float tsum = ws[0] + ws[1] + ws[2] + ws[3] + ws[4] + ws[5];
        atomicAdd(loss, tsum * (1.0f / (float)CHW));
    }
}

extern "C" void kernel_launch(void* const* d_in, const int* in_sizes, int n_in,
                              void* d_out, int out_size, void* d_ws, size_t ws_size,
                              hipStream_t stream)
{
    const float* inp  = (const float*)d_in[0];
    const float* tar  = (const float*)d_in[1];
    const float* rfp  = (const float*)d_in[2];
    const float* msrc = (const float*)d_in[3];
    const float* mtar = (const float*)d_in[4];
    // d_in[5] = target_data_eye (unused by the reference computation)
    const int* i0 = (const int*)d_in[6];
    const int* i1 = (const int*)d_in[7];
    const int* i2 = (const int*)d_in[8];
    const int* i3 = (const int*)d_in[9];
    int n = in_sizes[6];

    float* out0 = (float*)d_out;
    float* out1 = out0 + CHW;
    float* out2 = out1 + CHW;
    float* out3 = out2 + CHW;
    float* loss = out3 + CHW;

    // workspace layout
    unsigned int* ghist  = (unsigned int*)d_ws;                      // [0, 6144): 1536 u32
    unsigned int* bm     = (unsigned int*)((char*)d_ws + 8192);      // [8192, 139264): 32768 u32 bitmap (128 KB)
    unsigned int* pk_dst = (unsigned int*)((char*)d_ws + 139264);    // HH u32 (4 MB)
    unsigned int* pk_ref = pk_dst + HH;                              // HH u32 (4 MB)

    k_elementwise<<<(HH / 4 + 255) / 256, 256, 0, stream>>>(
        (const float4*)inp, (const float4*)tar, (const float4*)rfp,
        (const float4*)msrc, (const float4*)mtar,
        (float4*)out0, (float4*)out1, (float4*)out2,
        (uint4*)pk_dst, (uint4*)pk_ref, ghist, bm, loss);

    k_hist<<<HIST_BLOCKS, 512, 0, stream>>>(pk_dst, pk_ref, i0, i1, i2, i3, ghist, bm, n);

    k_finalize<<<FIN_BLOCKS, 384, 0, stream>>>(
        (const uint4*)ghist, bm, (const float4*)out1, (const float4*)out2,
        (float4*)out3, loss);
}